// Round 3
// baseline (264.837 us; speedup 1.0000x reference)
//
#include <hip/hip_runtime.h>

// Problem constants (from reference)
#define DIM_IN   2048
#define FEAT     128
#define KP1      16385      // NCE_N + 1
#define NDATA    100000
#define BATCH    64
#define RT       256        // rows per gemm tile
#define KC       16         // k per staging pass (8 passes of 16 = 128)
#define NPASS    (FEAT / KC)
#define NTILES   ((NDATA + RT - 1) / RT)   // 391
#define GCH      16         // k-chunks per (side,b) in gather kernel

constexpr float NCE_T_INV = 1.0f / 0.07f;
constexpr float M_CONST   = 16384.0f / 100000.0f;   // NCE_N / N_DATA
constexpr float EPS_C     = 1e-7f;

// ---------------------------------------------------------------------------
// Kernel 1: h = l2norm(feat @ w.T + b). Per-wave coalesced row dots.
// Block 0 additionally zeroes z[128] and out.
// ---------------------------------------------------------------------------
__global__ void __launch_bounds__(256) embed_kernel(
    const float* __restrict__ feat_s, const float* __restrict__ feat_t,
    const float* __restrict__ w_s, const float* __restrict__ b_s,
    const float* __restrict__ w_t, const float* __restrict__ b_t,
    float* __restrict__ v_out, float* __restrict__ z_zero,
    float* __restrict__ out_zero)
{
    const int blk  = blockIdx.x;      // side*64 + b
    const int side = blk >> 6;
    const int b    = blk & 63;
    const float* feat = (side == 0 ? feat_s : feat_t) + (size_t)b * DIM_IN;
    const float* w    = (side == 0 ? w_s : w_t);
    const float* bias = (side == 0 ? b_s : b_t);

    __shared__ float sfeat[DIM_IN];
    __shared__ float pre[FEAT];
    __shared__ float wsum[2];

    const int t = threadIdx.x;
    if (blk == 0) {                   // fold the memsets into this launch
        if (t < 128) z_zero[t] = 0.f;
        else if (t == 128) out_zero[0] = 0.f;
    }
    {   // coalesced float4 stage of the feat row (8 KB)
        const float4* f4 = (const float4*)feat;
        float4* s4 = (float4*)sfeat;
        for (int j = t; j < DIM_IN / 4; j += 256) s4[j] = f4[j];
    }
    __syncthreads();

    const int wv = t >> 6, ln = t & 63;
    const float4* w4  = (const float4*)w;
    const float4* sf4 = (const float4*)sfeat;
    for (int d = wv; d < FEAT; d += 4) {
        float s = 0.f;
#pragma unroll
        for (int seg = 0; seg < 8; ++seg) {      // 512 float4 per row / 64 lanes
            float4 a = w4[d * (DIM_IN / 4) + seg * 64 + ln];
            float4 f = sf4[seg * 64 + ln];
            s += a.x * f.x + a.y * f.y + a.z * f.z + a.w * f.w;
        }
#pragma unroll
        for (int o = 32; o > 0; o >>= 1) s += __shfl_xor(s, o, 64);
        if (ln == 0) pre[d] = s;
    }
    __syncthreads();

    if (t < 128) {
        float p = pre[t] + bias[t];
        pre[t] = p;
        float sq = p * p;
#pragma unroll
        for (int o = 32; o > 0; o >>= 1) sq += __shfl_xor(sq, o, 64);
        if ((t & 63) == 0) wsum[t >> 6] = sq;
    }
    __syncthreads();
    if (t < 128) {
        float inv_norm = 1.0f / sqrtf(wsum[0] + wsum[1]);
        v_out[(size_t)blk * FEAT + t] = pre[t] * inv_norm;
    }
}

// ---------------------------------------------------------------------------
// Kernel 2: dense skinny GEMM + exp. E[sb][n] = exp(dot/T).
// Round-2 post-mortem: dur identical at 2 vs 4 blocks/CU headroom, VALUBusy
// pinned at 35% = FMA floor -> stall is the per-pass stage->barrier(vmcnt(0)
// drain)->compute lockstep, NOT residency. Fix: DOUBLE-BUFFERED staging
// (T3 minimal 2-phase recipe): issue pass p+1's loads BEFORE computing pass
// p; one __syncthreads per pass whose vmcnt(0) drain lands after ~2000+ cyc
// of compute -> HBM latency hidden.
//  - KC=16, sA[2][256x16]+sB[2][16x64] = 40 KB -> 4 blocks/CU by LDS.
//  - A staged with global_load_lds (16B): linear LDS dest (wave base +
//    lane*16); XOR swizzle applied to the GLOBAL source (both-sides rule).
//    KC=16 bank math: row stride = 16 banks; read slot = (c ^ (rg&3))&3 ->
//    4 slot groups x 2 rg each = 2-way conflict = free (m136).
//  - sB reads 2-way aliased (free); thread tile 8 rows x 8 anchors.
// ---------------------------------------------------------------------------
__global__ void __launch_bounds__(256, 2) gemm_exp_kernel(
    const float* __restrict__ mem_v1, const float* __restrict__ mem_v2,
    const float* __restrict__ v_in, float* __restrict__ E)
{
    __shared__ __align__(16) float sA[2][RT * KC];   // 2 x 16 KB
    __shared__ __align__(16) float sB[2][KC * 64];   // 2 x 4 KB

    const int bx   = blockIdx.x;
    const int side = bx & 1;
    const int tile = bx >> 1;
    const int n0   = tile * RT;
    const float* bank = (side == 0 ? mem_v2 : mem_v1);
    const float* vb   = v_in + (size_t)side * 64 * FEAT;
    const int t  = threadIdx.x;
    const int ag = t & 7;             // anchor group: anchors ag*8..+7
    const int rg = t >> 3;            // row group:    rows n0+rg*8..+7
    const int r0 = n0 + rg * 8;

    const int wv   = t >> 6, ln = t & 63;
    const int rsub = ln >> 2;         // row within 16-row DMA chunk
    const int fst  = ln & 3;          // float4 slot in LDS row (linear dest)

    float acc[8][8];
#pragma unroll
    for (int i = 0; i < 8; ++i)
#pragma unroll
        for (int j = 0; j < 8; ++j) acc[i][j] = 0.f;

    // stage pass p into buffer bb: A via async DMA (4 x 1KB chunks per wave),
    // B via float4 load + 4 scalar ds_writes (bank=b2 -> 2-way, free).
    auto do_stage = [&](int p, int bb) {
#pragma unroll
        for (int j = 0; j < 4; ++j) {
            const int rl = wv * 64 + j * 16 + rsub;      // tile-local row
            int row = n0 + rl; if (row > NDATA - 1) row = NDATA - 1;
            const int fg = fst ^ ((rl >> 3) & 3);        // src pre-swizzle
            const float* src = bank + (size_t)row * FEAT + p * KC + fg * 4;
            float* dst = &sA[bb][(wv * 64 + j * 16) * KC];   // wave-uniform
            __builtin_amdgcn_global_load_lds(
                (const __attribute__((address_space(1))) void*)src,
                (__attribute__((address_space(3))) void*)dst, 16, 0, 0);
        }
        {
            const int b2 = t & 63;
            const int f  = t >> 6;                       // 0..3
            float4 v4 = *(const float4*)(vb + (size_t)b2 * FEAT + p * KC + f * 4);
            sB[bb][(f * 4 + 0) * 64 + b2] = v4.x;
            sB[bb][(f * 4 + 1) * 64 + b2] = v4.y;
            sB[bb][(f * 4 + 2) * 64 + b2] = v4.z;
            sB[bb][(f * 4 + 3) * 64 + b2] = v4.w;
        }
    };

    do_stage(0, 0);
    __syncthreads();                  // pass-0 data ready

#pragma unroll 1
    for (int p = 0; p < NPASS; ++p) {
        const int cur = p & 1;
        if (p + 1 < NPASS) do_stage(p + 1, cur ^ 1);   // issue-early (T14)

#pragma unroll 1
        for (int c = 0; c < KC / 4; ++c) {            // 4 chunks of 4 k
            float4 af[8], bf[8];
            const int ca = 4 * ((c ^ (rg & 3)) & 3);  // un-swizzle
#pragma unroll
            for (int i = 0; i < 8; ++i)
                af[i] = *(const float4*)&sA[cur][(rg * 8 + i) * KC + ca];
#pragma unroll
            for (int kk = 0; kk < 4; ++kk) {
                bf[kk * 2 + 0] = *(const float4*)&sB[cur][(c * 4 + kk) * 64 + ag * 8];
                bf[kk * 2 + 1] = *(const float4*)&sB[cur][(c * 4 + kk) * 64 + ag * 8 + 4];
            }
#pragma unroll
            for (int kk = 0; kk < 4; ++kk) {
#pragma unroll
                for (int i = 0; i < 8; ++i) {
                    const float a = (kk == 0) ? af[i].x : (kk == 1) ? af[i].y
                                  : (kk == 2) ? af[i].z : af[i].w;
                    acc[i][0] += a * bf[kk * 2].x;
                    acc[i][1] += a * bf[kk * 2].y;
                    acc[i][2] += a * bf[kk * 2].z;
                    acc[i][3] += a * bf[kk * 2].w;
                    acc[i][4] += a * bf[kk * 2 + 1].x;
                    acc[i][5] += a * bf[kk * 2 + 1].y;
                    acc[i][6] += a * bf[kk * 2 + 1].z;
                    acc[i][7] += a * bf[kk * 2 + 1].w;
                }
            }
        }
        __syncthreads();   // drains stage p+1 (landed under compute) +
                           // all waves done reading buffer cur
    }

    // epilogue: exp + store E[sb][n]; per anchor a wave's 8 same-ag lanes
    // cover 64 consecutive n (coalesced 256 B).
    if (r0 + 8 <= NDATA) {
#pragma unroll
        for (int j = 0; j < 8; ++j) {
            float4 o0, o1;
            o0.x = __expf(acc[0][j] * NCE_T_INV);
            o0.y = __expf(acc[1][j] * NCE_T_INV);
            o0.z = __expf(acc[2][j] * NCE_T_INV);
            o0.w = __expf(acc[3][j] * NCE_T_INV);
            o1.x = __expf(acc[4][j] * NCE_T_INV);
            o1.y = __expf(acc[5][j] * NCE_T_INV);
            o1.z = __expf(acc[6][j] * NCE_T_INV);
            o1.w = __expf(acc[7][j] * NCE_T_INV);
            float* dst = E + (size_t)(side * 64 + ag * 8 + j) * NDATA + r0;
            *(float4*)dst = o0;
            *(float4*)(dst + 4) = o1;
        }
    }
}

// ---------------------------------------------------------------------------
// Kernel 3: gather ex = E[sb][idx[b,k]], store compact, accumulate Z[sb].
// GCH=16: latency-bound random 4B reads; 32 waves in flight per CU.
// blk&127 = sb keeps a given sb's chunks on one XCD.
// ---------------------------------------------------------------------------
__global__ void __launch_bounds__(256) gather_z_kernel(
    const int* __restrict__ sample_idx, const float* __restrict__ E,
    float* __restrict__ ex_out, float* __restrict__ z_out)
{
    const int blk   = blockIdx.x;
    const int chunk = blk >> 7;          // 0..GCH-1
    const int sb    = blk & 127;         // side*64 + b
    const int b     = sb & 63;
    const float* Eb = E + (size_t)sb * NDATA;

    float zp = 0.f;
    for (int k = chunk * 256 + threadIdx.x; k < KP1; k += GCH * 256) {
        const int idx = sample_idx[(size_t)b * KP1 + k];
        const float e = Eb[idx];
        ex_out[(size_t)sb * KP1 + k] = e;
        zp += e;
    }
#pragma unroll
    for (int o = 32; o > 0; o >>= 1) zp += __shfl_xor(zp, o, 64);
    __shared__ float zw[4];
    if ((threadIdx.x & 63) == 0) zw[threadIdx.x >> 6] = zp;
    __syncthreads();
    if (threadIdx.x == 0) atomicAdd(&z_out[sb], zw[0] + zw[1] + zw[2] + zw[3]);
}

// ---------------------------------------------------------------------------
// Kernel 4: loss. 256 blocks (2 chunks x 128 sb). Z summed in-kernel from
// the 64 per-sb partials of this side; 256 output atomics total.
// ---------------------------------------------------------------------------
__global__ void __launch_bounds__(256) loss_kernel(
    const float* __restrict__ ex_in, const float* __restrict__ z_in,
    float* __restrict__ out)
{
    const int blk   = blockIdx.x;
    const int chunk = blk >> 7;          // 0..1
    const int sb    = blk & 127;
    const int side  = sb >> 6;

    __shared__ float zsh;
    if (threadIdx.x < 64) {
        float zv = z_in[side * 64 + threadIdx.x];
#pragma unroll
        for (int o = 32; o > 0; o >>= 1) zv += __shfl_xor(zv, o, 64);
        if (threadIdx.x == 0) zsh = zv;
    }
    __syncthreads();

    const float z  = zsh * ((float)NDATA / (64.0f * (float)KP1));
    const float rz = 1.0f / z;
    const float* ex = ex_in + (size_t)sb * KP1;

    float part = 0.f;
    for (int k = chunk * 256 + threadIdx.x; k < KP1; k += 512) {
        const float x = ex[k] * rz;
        if (k == 0) part += __logf(x / (x + M_CONST + EPS_C));
        else        part += __logf(M_CONST / (x + M_CONST + EPS_C));
    }
#pragma unroll
    for (int o = 32; o > 0; o >>= 1) part += __shfl_xor(part, o, 64);
    __shared__ float pw[4];
    if ((threadIdx.x & 63) == 0) pw[threadIdx.x >> 6] = part;
    __syncthreads();
    if (threadIdx.x == 0)
        atomicAdd(out, -(pw[0] + pw[1] + pw[2] + pw[3]) * (1.0f / 64.0f));
}

// ---------------------------------------------------------------------------
extern "C" void kernel_launch(void* const* d_in, const int* in_sizes, int n_in,
                              void* d_out, int out_size, void* d_ws, size_t ws_size,
                              hipStream_t stream)
{
    const float* feat_s     = (const float*)d_in[0];
    const float* feat_t     = (const float*)d_in[1];
    /* d_in[2] = idx, unused: sample_idx[:,0] already holds it */
    const int*   sample_idx = (const int*)  d_in[3];
    const float* w_s        = (const float*)d_in[4];
    const float* b_s        = (const float*)d_in[5];
    const float* w_t        = (const float*)d_in[6];
    const float* b_t        = (const float*)d_in[7];
    const float* mem_v1     = (const float*)d_in[8];
    const float* mem_v2     = (const float*)d_in[9];
    float* out = (float*)d_out;

    // Workspace layout:
    //   [z: 128 f32 = 512 B]
    //   [v: 2*64*128 f32 = 64 KB]
    //   [ex: 2*64*16385 f32 = 8.39 MB]
    //   [E: 128*100000 f32 = 51.2 MB]  (transposed: E[sb][n])
    char*  ws    = (char*)d_ws;
    float* ws_z  = (float*)ws;
    float* ws_v  = (float*)(ws + 512);
    float* ws_ex = (float*)(ws + 512 + 2 * BATCH * FEAT * sizeof(float));
    float* ws_E  = (float*)(ws + 512 + 2 * BATCH * FEAT * sizeof(float)
                               + (size_t)2 * BATCH * KP1 * sizeof(float));

    // z/out zeroing folded into embed_kernel block 0 (saves 2 graph nodes)
    embed_kernel<<<2 * BATCH, 256, 0, stream>>>(feat_s, feat_t, w_s, b_s, w_t, b_t,
                                                ws_v, ws_z, out);
    gemm_exp_kernel<<<2 * NTILES, 256, 0, stream>>>(mem_v1, mem_v2, ws_v, ws_E);
    gather_z_kernel<<<2 * BATCH * GCH, 256, 0, stream>>>(sample_idx, ws_E, ws_ex, ws_z);
    loss_kernel<<<2 * BATCH * 2, 256, 0, stream>>>(ws_ex, ws_z, out);
}

// Round 4
// 234.844 us; speedup vs baseline: 1.1277x; 1.1277x over previous
//
#include <hip/hip_runtime.h>

// Problem constants (from reference)
#define DIM_IN   2048
#define FEAT     128
#define KP1      16385      // NCE_N + 1
#define NDATA    100000
#define BATCH    64
#define NB       128        // bank rows per gemm block
#define NBLK     ((NDATA + NB - 1) / NB)   // 782
#define GCH      16         // k-chunks per (side,b) in gather kernel

constexpr float NCE_T_INV = 1.0f / 0.07f;
constexpr float M_CONST   = 16384.0f / 100000.0f;   // NCE_N / N_DATA
constexpr float EPS_C     = 1e-7f;

typedef short bf16x8 __attribute__((ext_vector_type(8)));   // 8 bf16 = 4 VGPR
typedef float f32x4  __attribute__((ext_vector_type(4)));   // MFMA acc

// vplanes global layout (bytes), written by embed, DMA'd linearly by gemm:
//   plane(hi=0,lo=1)*34816 + side*17408 + anchor*272 + k*2
// 272 = 256 (128 k * 2B) + 16 pad -> 17-quad row stride, 17%8 coprime-ish
// (17 == 1 mod 8) -> fragment reads spread uniformly over bank-quads.
#define VP_PLANE 34816
#define VP_SIDE  17408
#define VP_ROW   272

// ---------------------------------------------------------------------------
// Kernel 1: h = l2norm(feat @ w.T + b), emitted as SPLIT-bf16 planes:
// hi = trunc16(x), lo = trunc16(x - hi); hi+lo represents x to ~2^-16 rel.
// Block 0 additionally zeroes z[128] and out.
// ---------------------------------------------------------------------------
__global__ void __launch_bounds__(256) embed_kernel(
    const float* __restrict__ feat_s, const float* __restrict__ feat_t,
    const float* __restrict__ w_s, const float* __restrict__ b_s,
    const float* __restrict__ w_t, const float* __restrict__ b_t,
    char* __restrict__ vplanes, float* __restrict__ z_zero,
    float* __restrict__ out_zero)
{
    const int blk  = blockIdx.x;      // side*64 + b
    const int side = blk >> 6;
    const int b    = blk & 63;
    const float* feat = (side == 0 ? feat_s : feat_t) + (size_t)b * DIM_IN;
    const float* w    = (side == 0 ? w_s : w_t);
    const float* bias = (side == 0 ? b_s : b_t);

    __shared__ float sfeat[DIM_IN];
    __shared__ float pre[FEAT];
    __shared__ float wsum[2];

    const int t = threadIdx.x;
    if (blk == 0) {                   // fold the memsets into this launch
        if (t < 128) z_zero[t] = 0.f;
        else if (t == 128) out_zero[0] = 0.f;
    }
    {   // coalesced float4 stage of the feat row (8 KB)
        const float4* f4 = (const float4*)feat;
        float4* s4 = (float4*)sfeat;
        for (int j = t; j < DIM_IN / 4; j += 256) s4[j] = f4[j];
    }
    __syncthreads();

    const int wv = t >> 6, ln = t & 63;
    const float4* w4  = (const float4*)w;
    const float4* sf4 = (const float4*)sfeat;
    for (int d = wv; d < FEAT; d += 4) {
        float s = 0.f;
#pragma unroll
        for (int seg = 0; seg < 8; ++seg) {      // 512 float4 per row / 64 lanes
            float4 a = w4[d * (DIM_IN / 4) + seg * 64 + ln];
            float4 f = sf4[seg * 64 + ln];
            s += a.x * f.x + a.y * f.y + a.z * f.z + a.w * f.w;
        }
#pragma unroll
        for (int o = 32; o > 0; o >>= 1) s += __shfl_xor(s, o, 64);
        if (ln == 0) pre[d] = s;
    }
    __syncthreads();

    if (t < 128) {
        float p = pre[t] + bias[t];
        pre[t] = p;
        float sq = p * p;
#pragma unroll
        for (int o = 32; o > 0; o >>= 1) sq += __shfl_xor(sq, o, 64);
        if ((t & 63) == 0) wsum[t >> 6] = sq;
    }
    __syncthreads();
    if (t < 128) {
        float inv_norm = 1.0f / sqrtf(wsum[0] + wsum[1]);
        float x = pre[t] * inv_norm;
        unsigned int u = __float_as_uint(x);
        unsigned short h = (unsigned short)(u >> 16);
        float hf = __uint_as_float(u & 0xffff0000u);
        float lr = x - hf;                         // exact in fp32
        unsigned short l = (unsigned short)(__float_as_uint(lr) >> 16);
        const size_t off = (size_t)side * VP_SIDE + (size_t)b * VP_ROW + t * 2;
        *(unsigned short*)(vplanes + off)            = h;
        *(unsigned short*)(vplanes + VP_PLANE + off) = l;
    }
}

// ---------------------------------------------------------------------------
// Kernel 2 (MFMA REWRITE): E[sb][n] = exp(dot(bank[n], v[sb]) / T).
// Rounds 0-3 showed the fp32-VALU inner loop is at its structural floor
// (~71 us invariant across 3 staging schemes; LDS delivers ~2 MB/block at
// 1 B per FMA, FMA issue floor 21 us). Switch to the matrix pipe via
// split-precision bf16x3: x = hi + lo (each bf16), C = Ah*Bh + Al*Bh + Ah*Bl
// (dropped Al*Bl ~ 2^-16 = representation error) -> fp32-grade dots at
// 3x bf16 MFMA rate = ~4.6 us of matrix time; kernel becomes memory-bound.
//   - M = anchors (64/side, 4 m-tiles), N = 128 bank rows (8 n-tiles,
//     1 per wave), K = 128 in 4 chunks of 32 (mfma_f32_16x16x32_bf16).
//   - A (v planes): converted once in embed, padded-272B rows, DMA'd
//     linearly into LDS (global_load_lds; layout identical by construction).
//     Frag read quads = (lm + kb + 4c) % 8 -> uniform, conflict-free.
//   - B (bank rows): reg-staged fp32 -> split hi/lo -> ds_write into
//     80B-padded rows (5 coprime 8 -> quads 5r+q uniform, write & read
//     conflict-free). Double-buffered, issue-early/write-late (T14).
//   - C/D layout (verified m89): col=lane&15 -> bank row (contiguous E
//     stores), row=(lane>>4)*4+reg -> anchor.
// LDS 75776 B -> 2 blocks/CU (512 thr = 16 waves/CU).
// ---------------------------------------------------------------------------
__global__ void __launch_bounds__(512) gemm_exp_kernel(
    const float* __restrict__ mem_v1, const float* __restrict__ mem_v2,
    const char* __restrict__ vplanes, float* __restrict__ E)
{
    // LDS map (bytes):
    //   [0,17408)        A hi  : anchor*272 + k*2
    //   [17408,34816)    A lo
    //   [34816,+20480)   B buf0: plane*10240 + row*80 + k*2
    //   [55296,+20480)   B buf1
    __shared__ __align__(16) char lds[75776];

    const int bx   = blockIdx.x;
    const int side = bx & 1;
    const int tile = bx >> 1;
    const int n0   = tile * NB;
    const float* bank = (side == 0 ? mem_v2 : mem_v1);
    const int t  = threadIdx.x;
    const int wv = t >> 6, ln = t & 63;
    const int lm = ln & 15;           // MFMA lane row/col index
    const int kb = ln >> 4;           // MFMA k-block (0..3)

    // ---- A planes: linear DMA, 34 segments x 1024 B --------------------
    {
        const char* hbase = vplanes + (size_t)side * VP_SIDE;
        const char* lbase = vplanes + VP_PLANE + (size_t)side * VP_SIDE;
        for (int seg = wv; seg < 34; seg += 8) {
            const char* src = (seg < 17 ? hbase + seg * 1024
                                        : lbase + (seg - 17) * 1024) + ln * 16;
            __builtin_amdgcn_global_load_lds(
                (const __attribute__((address_space(1))) void*)src,
                (__attribute__((address_space(3))) void*)(lds + seg * 1024),
                16, 0, 0);
        }
    }

    // ---- B staging geometry: thread -> (row r, k-quad q) ---------------
    const int r = t >> 2;             // 0..127 (tile-local bank row)
    const int q = t & 3;              // 0..3   (8-float group within chunk)
    int rowg = n0 + r; if (rowg > NDATA - 1) rowg = NDATA - 1;
    const float* bsrc = bank + (size_t)rowg * FEAT;

    f32x4 acc[4];
#pragma unroll
    for (int mi = 0; mi < 4; ++mi) acc[mi] = (f32x4){0.f, 0.f, 0.f, 0.f};

    // chunk 0 stage
    float4 sa, sb;
    {
        const float4* p = (const float4*)(bsrc + 0 * 32 + q * 8);
        sa = p[0]; sb = p[1];
    }
    {
        float xs[8] = {sa.x, sa.y, sa.z, sa.w, sb.x, sb.y, sb.z, sb.w};
        bf16x8 H, L;
#pragma unroll
        for (int j = 0; j < 8; ++j) {
            unsigned int u = __float_as_uint(xs[j]);
            H[j] = (short)(u >> 16);
            float hf = __uint_as_float(u & 0xffff0000u);
            L[j] = (short)(__float_as_uint(xs[j] - hf) >> 16);
        }
        char* base = lds + 34816;                  // buf 0
        *(bf16x8*)(base + r * 80 + q * 16) = H;
        *(bf16x8*)(base + 10240 + r * 80 + q * 16) = L;
    }
    __syncthreads();    // A DMA (vmcnt) + B0 ds_writes drained

    const int nloc = wv * 16 + lm;    // tile-local bank row this lane outputs

#pragma unroll 1
    for (int c = 0; c < 4; ++c) {
        // issue-early: next chunk's global loads (consumed after MFMA)
        float4 na, nb;
        if (c < 3) {
            const float4* p = (const float4*)(bsrc + (c + 1) * 32 + q * 8);
            na = p[0]; nb = p[1];
        }
        // fragments
        bf16x8 ah[4], al[4];
#pragma unroll
        for (int mi = 0; mi < 4; ++mi) {
            ah[mi] = *(const bf16x8*)(lds + (mi * 16 + lm) * VP_ROW + c * 64 + kb * 16);
            al[mi] = *(const bf16x8*)(lds + 17408 + (mi * 16 + lm) * VP_ROW + c * 64 + kb * 16);
        }
        const char* bb = lds + 34816 + (c & 1) * 20480;
        bf16x8 bh = *(const bf16x8*)(bb + nloc * 80 + kb * 16);
        bf16x8 bl = *(const bf16x8*)(bb + 10240 + nloc * 80 + kb * 16);

        // 3-term split-precision MFMA
#pragma unroll
        for (int mi = 0; mi < 4; ++mi) {
            acc[mi] = __builtin_amdgcn_mfma_f32_16x16x32_bf16(ah[mi], bh, acc[mi], 0, 0, 0);
            acc[mi] = __builtin_amdgcn_mfma_f32_16x16x32_bf16(al[mi], bh, acc[mi], 0, 0, 0);
            acc[mi] = __builtin_amdgcn_mfma_f32_16x16x32_bf16(ah[mi], bl, acc[mi], 0, 0, 0);
        }

        // write-late: convert + ds_write next chunk into the other buffer
        if (c < 3) {
            float xs[8] = {na.x, na.y, na.z, na.w, nb.x, nb.y, nb.z, nb.w};
            bf16x8 H, L;
#pragma unroll
            for (int j = 0; j < 8; ++j) {
                unsigned int u = __float_as_uint(xs[j]);
                H[j] = (short)(u >> 16);
                float hf = __uint_as_float(u & 0xffff0000u);
                L[j] = (short)(__float_as_uint(xs[j] - hf) >> 16);
            }
            char* base = lds + 34816 + ((c + 1) & 1) * 20480;
            *(bf16x8*)(base + r * 80 + q * 16) = H;
            *(bf16x8*)(base + 10240 + r * 80 + q * 16) = L;
        }
        __syncthreads();
    }

    // epilogue: exp + store. col=lane&15 -> n (16 consecutive per 16-lane
    // group = 64 B segments), row=(lane>>4)*4+reg -> anchor.
    const int nn = n0 + nloc;
    if (nn < NDATA) {
#pragma unroll
        for (int mi = 0; mi < 4; ++mi)
#pragma unroll
            for (int j = 0; j < 4; ++j) {
                const int anchor = mi * 16 + kb * 4 + j;
                E[(size_t)(side * 64 + anchor) * NDATA + nn] =
                    __expf(acc[mi][j] * NCE_T_INV);
            }
    }
}

// ---------------------------------------------------------------------------
// Kernel 3: gather ex = E[sb][idx[b,k]], store compact, accumulate Z[sb].
// GCH=16: latency-bound random 4B reads; 32 waves in flight per CU.
// blk&127 = sb keeps a given sb's chunks on one XCD.
// ---------------------------------------------------------------------------
__global__ void __launch_bounds__(256) gather_z_kernel(
    const int* __restrict__ sample_idx, const float* __restrict__ E,
    float* __restrict__ ex_out, float* __restrict__ z_out)
{
    const int blk   = blockIdx.x;
    const int chunk = blk >> 7;          // 0..GCH-1
    const int sb    = blk & 127;         // side*64 + b
    const int b     = sb & 63;
    const float* Eb = E + (size_t)sb * NDATA;

    float zp = 0.f;
    for (int k = chunk * 256 + threadIdx.x; k < KP1; k += GCH * 256) {
        const int idx = sample_idx[(size_t)b * KP1 + k];
        const float e = Eb[idx];
        ex_out[(size_t)sb * KP1 + k] = e;
        zp += e;
    }
#pragma unroll
    for (int o = 32; o > 0; o >>= 1) zp += __shfl_xor(zp, o, 64);
    __shared__ float zw[4];
    if ((threadIdx.x & 63) == 0) zw[threadIdx.x >> 6] = zp;
    __syncthreads();
    if (threadIdx.x == 0) atomicAdd(&z_out[sb], zw[0] + zw[1] + zw[2] + zw[3]);
}

// ---------------------------------------------------------------------------
// Kernel 4: loss. 256 blocks (2 chunks x 128 sb). Z summed in-kernel from
// the 64 per-sb partials of this side; 256 output atomics total.
// ---------------------------------------------------------------------------
__global__ void __launch_bounds__(256) loss_kernel(
    const float* __restrict__ ex_in, const float* __restrict__ z_in,
    float* __restrict__ out)
{
    const int blk   = blockIdx.x;
    const int chunk = blk >> 7;          // 0..1
    const int sb    = blk & 127;
    const int side  = sb >> 6;

    __shared__ float zsh;
    if (threadIdx.x < 64) {
        float zv = z_in[side * 64 + threadIdx.x];
#pragma unroll
        for (int o = 32; o > 0; o >>= 1) zv += __shfl_xor(zv, o, 64);
        if (threadIdx.x == 0) zsh = zv;
    }
    __syncthreads();

    const float z  = zsh * ((float)NDATA / (64.0f * (float)KP1));
    const float rz = 1.0f / z;
    const float* ex = ex_in + (size_t)sb * KP1;

    float part = 0.f;
    for (int k = chunk * 256 + threadIdx.x; k < KP1; k += 512) {
        const float x = ex[k] * rz;
        if (k == 0) part += __logf(x / (x + M_CONST + EPS_C));
        else        part += __logf(M_CONST / (x + M_CONST + EPS_C));
    }
#pragma unroll
    for (int o = 32; o > 0; o >>= 1) part += __shfl_xor(part, o, 64);
    __shared__ float pw[4];
    if ((threadIdx.x & 63) == 0) pw[threadIdx.x >> 6] = part;
    __syncthreads();
    if (threadIdx.x == 0)
        atomicAdd(out, -(pw[0] + pw[1] + pw[2] + pw[3]) * (1.0f / 64.0f));
}

// ---------------------------------------------------------------------------
extern "C" void kernel_launch(void* const* d_in, const int* in_sizes, int n_in,
                              void* d_out, int out_size, void* d_ws, size_t ws_size,
                              hipStream_t stream)
{
    const float* feat_s     = (const float*)d_in[0];
    const float* feat_t     = (const float*)d_in[1];
    /* d_in[2] = idx, unused: sample_idx[:,0] already holds it */
    const int*   sample_idx = (const int*)  d_in[3];
    const float* w_s        = (const float*)d_in[4];
    const float* b_s        = (const float*)d_in[5];
    const float* w_t        = (const float*)d_in[6];
    const float* b_t        = (const float*)d_in[7];
    const float* mem_v1     = (const float*)d_in[8];
    const float* mem_v2     = (const float*)d_in[9];
    float* out = (float*)d_out;

    // Workspace layout:
    //   [z: 128 f32 = 512 B]
    //   [ex: 2*64*16385 f32 = 8.39 MB]   (gather-write -> loss-read)
    //   [vplanes: 69632 B, ALIASES ex]   (embed-write -> gemm-read; lifetimes
    //                                     disjoint: gemm ends before gather)
    //   [E: 128*100000 f32 = 51.2 MB]    (transposed: E[sb][n])
    char*  ws     = (char*)d_ws;
    float* ws_z   = (float*)ws;
    float* ws_ex  = (float*)(ws + 512);
    char*  ws_vp  = (char*)(ws + 512);   // alias of ex region
    float* ws_E   = (float*)(ws + 512 + (size_t)2 * BATCH * KP1 * sizeof(float));

    // z/out zeroing folded into embed_kernel block 0
    embed_kernel<<<2 * BATCH, 256, 0, stream>>>(feat_s, feat_t, w_s, b_s, w_t, b_t,
                                                ws_vp, ws_z, out);
    gemm_exp_kernel<<<2 * NBLK, 512, 0, stream>>>(mem_v1, mem_v2, ws_vp, ws_E);
    gather_z_kernel<<<2 * BATCH * GCH, 256, 0, stream>>>(sample_idx, ws_E, ws_ex, ws_z);
    loss_kernel<<<2 * BATCH * 2, 256, 0, stream>>>(ws_ex, ws_z, out);
}

// Round 5
// 204.684 us; speedup vs baseline: 1.2939x; 1.1473x over previous
//
#include <hip/hip_runtime.h>

// Problem constants (from reference)
#define DIM_IN   2048
#define FEAT     128
#define KP1      16385      // NCE_N + 1
#define NDATA    100000
#define BATCH    64
#define NB       128        // bank rows per gemm block
#define NBLK     ((NDATA + NB - 1) / NB)   // 782
#define GCH      16         // k-chunks per (side,b) in gather kernel

constexpr float NCE_T_INV = 1.0f / 0.07f;
constexpr float M_CONST   = 16384.0f / 100000.0f;   // NCE_N / N_DATA
constexpr float EPS_C     = 1e-7f;

typedef short bf16x8 __attribute__((ext_vector_type(8)));   // 8 bf16 = 4 VGPR
typedef float f32x4  __attribute__((ext_vector_type(4)));   // MFMA acc

// vplanes global layout (bytes), written by embed, DMA'd linearly by gemm:
//   plane(hi=0,lo=1)*34816 + side*17408 + anchor*272 + k*2
#define VP_PLANE 34816
#define VP_SIDE  17408
#define VP_ROW   272

// ---------------------------------------------------------------------------
// Kernel 1: h = l2norm(feat @ w.T + b), emitted as SPLIT-bf16 planes.
// Round-4 post-mortem: 50 us at VALUBusy 2.5%, occupancy 5% -- 256 threads x
// 128 blocks = 1 wave/SIMD on half the chip, 32 serial load-gated d-iters.
// FIX: 1024 threads (16 waves): d-loop 32 -> 8 iters, 4 waves/SIMD of TLP.
// Block count stays 128 (l2norm needs all 128 dims in-block).
// Block 0 additionally zeroes z[128] and out.
// ---------------------------------------------------------------------------
__global__ void __launch_bounds__(1024) embed_kernel(
    const float* __restrict__ feat_s, const float* __restrict__ feat_t,
    const float* __restrict__ w_s, const float* __restrict__ b_s,
    const float* __restrict__ w_t, const float* __restrict__ b_t,
    char* __restrict__ vplanes, float* __restrict__ z_zero,
    float* __restrict__ out_zero)
{
    const int blk  = blockIdx.x;      // side*64 + b
    const int side = blk >> 6;
    const int b    = blk & 63;
    const float* feat = (side == 0 ? feat_s : feat_t) + (size_t)b * DIM_IN;
    const float* w    = (side == 0 ? w_s : w_t);
    const float* bias = (side == 0 ? b_s : b_t);

    __shared__ float sfeat[DIM_IN];
    __shared__ float pre[FEAT];
    __shared__ float wsum[2];

    const int t = threadIdx.x;
    if (blk == 0) {                   // fold the memsets into this launch
        if (t < 128) z_zero[t] = 0.f;
        else if (t == 128) out_zero[0] = 0.f;
    }
    {   // coalesced float4 stage of the feat row (8 KB, 512 float4)
        const float4* f4 = (const float4*)feat;
        float4* s4 = (float4*)sfeat;
        if (t < 512) s4[t] = f4[t];
    }
    __syncthreads();

    const int wv = t >> 6, ln = t & 63;   // 16 waves
    const float4* w4  = (const float4*)w;
    const float4* sf4 = (const float4*)sfeat;
#pragma unroll 2
    for (int i = 0; i < 8; ++i) {         // d = wv + 16*i: 8 iters/wave
        const int d = wv + i * 16;
        float s = 0.f;
#pragma unroll
        for (int seg = 0; seg < 8; ++seg) {  // 512 float4 per row / 64 lanes
            float4 a = w4[d * (DIM_IN / 4) + seg * 64 + ln];
            float4 f = sf4[seg * 64 + ln];
            s += a.x * f.x + a.y * f.y + a.z * f.z + a.w * f.w;
        }
#pragma unroll
        for (int o = 32; o > 0; o >>= 1) s += __shfl_xor(s, o, 64);
        if (ln == 0) pre[d] = s;
    }
    __syncthreads();

    if (t < 128) {
        float p = pre[t] + bias[t];
        pre[t] = p;
        float sq = p * p;
#pragma unroll
        for (int o = 32; o > 0; o >>= 1) sq += __shfl_xor(sq, o, 64);
        if ((t & 63) == 0) wsum[t >> 6] = sq;
    }
    __syncthreads();
    if (t < 128) {
        float inv_norm = 1.0f / sqrtf(wsum[0] + wsum[1]);
        float x = pre[t] * inv_norm;
        unsigned int u = __float_as_uint(x);
        unsigned short h = (unsigned short)(u >> 16);
        float hf = __uint_as_float(u & 0xffff0000u);
        float lr = x - hf;                         // exact in fp32
        unsigned short l = (unsigned short)(__float_as_uint(lr) >> 16);
        const size_t off = (size_t)side * VP_SIDE + (size_t)b * VP_ROW + t * 2;
        *(unsigned short*)(vplanes + off)            = h;
        *(unsigned short*)(vplanes + VP_PLANE + off) = l;
    }
}

// ---------------------------------------------------------------------------
// Kernel 2 (MFMA, round-4 verified): E[sb][n] = exp(dot(bank[n], v[sb])/T).
// Split-precision bf16x3: C = Ah*Bh + Al*Bh + Ah*Bl at 3x bf16 MFMA rate.
//   - M = anchors (4 m-tiles), N = 128 bank rows (1/wave), K = 128 in 4
//     chunks of 32 (mfma_f32_16x16x32_bf16).
//   - A: vplanes padded-272B rows DMA'd linearly (global_load_lds).
//   - B: reg-staged fp32 -> split hi/lo -> ds_write 80B-padded rows,
//     double-buffered, issue-early/write-late (T14).
//   - C/D: col=lane&15 -> bank row, row=(lane>>4)*4+reg -> anchor (m89).
// LDS 75776 B -> 2 blocks/CU (512 thr).
// ---------------------------------------------------------------------------
__global__ void __launch_bounds__(512) gemm_exp_kernel(
    const float* __restrict__ mem_v1, const float* __restrict__ mem_v2,
    const char* __restrict__ vplanes, float* __restrict__ E)
{
    // LDS map (bytes):
    //   [0,17408)        A hi  : anchor*272 + k*2
    //   [17408,34816)    A lo
    //   [34816,+20480)   B buf0: plane*10240 + row*80 + k*2
    //   [55296,+20480)   B buf1
    __shared__ __align__(16) char lds[75776];

    const int bx   = blockIdx.x;
    const int side = bx & 1;
    const int tile = bx >> 1;
    const int n0   = tile * NB;
    const float* bank = (side == 0 ? mem_v2 : mem_v1);
    const int t  = threadIdx.x;
    const int wv = t >> 6, ln = t & 63;
    const int lm = ln & 15;           // MFMA lane row/col index
    const int kb = ln >> 4;           // MFMA k-block (0..3)

    // ---- A planes: linear DMA, 34 segments x 1024 B --------------------
    {
        const char* hbase = vplanes + (size_t)side * VP_SIDE;
        const char* lbase = vplanes + VP_PLANE + (size_t)side * VP_SIDE;
        for (int seg = wv; seg < 34; seg += 8) {
            const char* src = (seg < 17 ? hbase + seg * 1024
                                        : lbase + (seg - 17) * 1024) + ln * 16;
            __builtin_amdgcn_global_load_lds(
                (const __attribute__((address_space(1))) void*)src,
                (__attribute__((address_space(3))) void*)(lds + seg * 1024),
                16, 0, 0);
        }
    }

    // ---- B staging geometry: thread -> (row r, k-quad q) ---------------
    const int r = t >> 2;             // 0..127 (tile-local bank row)
    const int q = t & 3;              // 0..3   (8-float group within chunk)
    int rowg = n0 + r; if (rowg > NDATA - 1) rowg = NDATA - 1;
    const float* bsrc = bank + (size_t)rowg * FEAT;

    f32x4 acc[4];
#pragma unroll
    for (int mi = 0; mi < 4; ++mi) acc[mi] = (f32x4){0.f, 0.f, 0.f, 0.f};

    // chunk 0 stage
    float4 sa, sb;
    {
        const float4* p = (const float4*)(bsrc + 0 * 32 + q * 8);
        sa = p[0]; sb = p[1];
    }
    {
        float xs[8] = {sa.x, sa.y, sa.z, sa.w, sb.x, sb.y, sb.z, sb.w};
        bf16x8 H, L;
#pragma unroll
        for (int j = 0; j < 8; ++j) {
            unsigned int u = __float_as_uint(xs[j]);
            H[j] = (short)(u >> 16);
            float hf = __uint_as_float(u & 0xffff0000u);
            L[j] = (short)(__float_as_uint(xs[j] - hf) >> 16);
        }
        char* base = lds + 34816;                  // buf 0
        *(bf16x8*)(base + r * 80 + q * 16) = H;
        *(bf16x8*)(base + 10240 + r * 80 + q * 16) = L;
    }
    __syncthreads();    // A DMA (vmcnt) + B0 ds_writes drained

    const int nloc = wv * 16 + lm;    // tile-local bank row this lane outputs

#pragma unroll 1
    for (int c = 0; c < 4; ++c) {
        // issue-early: next chunk's global loads (consumed after MFMA)
        float4 na, nb;
        if (c < 3) {
            const float4* p = (const float4*)(bsrc + (c + 1) * 32 + q * 8);
            na = p[0]; nb = p[1];
        }
        // fragments
        bf16x8 ah[4], al[4];
#pragma unroll
        for (int mi = 0; mi < 4; ++mi) {
            ah[mi] = *(const bf16x8*)(lds + (mi * 16 + lm) * VP_ROW + c * 64 + kb * 16);
            al[mi] = *(const bf16x8*)(lds + 17408 + (mi * 16 + lm) * VP_ROW + c * 64 + kb * 16);
        }
        const char* bb = lds + 34816 + (c & 1) * 20480;
        bf16x8 bh = *(const bf16x8*)(bb + nloc * 80 + kb * 16);
        bf16x8 bl = *(const bf16x8*)(bb + 10240 + nloc * 80 + kb * 16);

        // 3-term split-precision MFMA
#pragma unroll
        for (int mi = 0; mi < 4; ++mi) {
            acc[mi] = __builtin_amdgcn_mfma_f32_16x16x32_bf16(ah[mi], bh, acc[mi], 0, 0, 0);
            acc[mi] = __builtin_amdgcn_mfma_f32_16x16x32_bf16(al[mi], bh, acc[mi], 0, 0, 0);
            acc[mi] = __builtin_amdgcn_mfma_f32_16x16x32_bf16(ah[mi], bl, acc[mi], 0, 0, 0);
        }

        // write-late: convert + ds_write next chunk into the other buffer
        if (c < 3) {
            float xs[8] = {na.x, na.y, na.z, na.w, nb.x, nb.y, nb.z, nb.w};
            bf16x8 H, L;
#pragma unroll
            for (int j = 0; j < 8; ++j) {
                unsigned int u = __float_as_uint(xs[j]);
                H[j] = (short)(u >> 16);
                float hf = __uint_as_float(u & 0xffff0000u);
                L[j] = (short)(__float_as_uint(xs[j] - hf) >> 16);
            }
            char* base = lds + 34816 + ((c + 1) & 1) * 20480;
            *(bf16x8*)(base + r * 80 + q * 16) = H;
            *(bf16x8*)(base + 10240 + r * 80 + q * 16) = L;
        }
        __syncthreads();
    }

    // epilogue: exp + store. col=lane&15 -> n, row=(lane>>4)*4+reg -> anchor.
    const int nn = n0 + nloc;
    if (nn < NDATA) {
#pragma unroll
        for (int mi = 0; mi < 4; ++mi)
#pragma unroll
            for (int j = 0; j < 4; ++j) {
                const int anchor = mi * 16 + kb * 4 + j;
                E[(size_t)(side * 64 + anchor) * NDATA + nn] =
                    __expf(acc[mi][j] * NCE_T_INV);
            }
    }
}

// ---------------------------------------------------------------------------
// Kernel 3: gather ex = E[sb][idx[b,k]], store compact, accumulate Z[sb].
// GCH=16: latency-bound random 4B reads; 32 waves in flight per CU.
// blk&127 = sb keeps a given sb's chunks on one XCD.
// ---------------------------------------------------------------------------
__global__ void __launch_bounds__(256) gather_z_kernel(
    const int* __restrict__ sample_idx, const float* __restrict__ E,
    float* __restrict__ ex_out, float* __restrict__ z_out)
{
    const int blk   = blockIdx.x;
    const int chunk = blk >> 7;          // 0..GCH-1
    const int sb    = blk & 127;         // side*64 + b
    const int b     = sb & 63;
    const float* Eb = E + (size_t)sb * NDATA;

    float zp = 0.f;
    for (int k = chunk * 256 + threadIdx.x; k < KP1; k += GCH * 256) {
        const int idx = sample_idx[(size_t)b * KP1 + k];
        const float e = Eb[idx];
        ex_out[(size_t)sb * KP1 + k] = e;
        zp += e;
    }
#pragma unroll
    for (int o = 32; o > 0; o >>= 1) zp += __shfl_xor(zp, o, 64);
    __shared__ float zw[4];
    if ((threadIdx.x & 63) == 0) zw[threadIdx.x >> 6] = zp;
    __syncthreads();
    if (threadIdx.x == 0) atomicAdd(&z_out[sb], zw[0] + zw[1] + zw[2] + zw[3]);
}

// ---------------------------------------------------------------------------
// Kernel 4: loss. 256 blocks (2 chunks x 128 sb). Z summed in-kernel from
// the 64 per-sb partials of this side; 256 output atomics total.
// ---------------------------------------------------------------------------
__global__ void __launch_bounds__(256) loss_kernel(
    const float* __restrict__ ex_in, const float* __restrict__ z_in,
    float* __restrict__ out)
{
    const int blk   = blockIdx.x;
    const int chunk = blk >> 7;          // 0..1
    const int sb    = blk & 127;
    const int side  = sb >> 6;

    __shared__ float zsh;
    if (threadIdx.x < 64) {
        float zv = z_in[side * 64 + threadIdx.x];
#pragma unroll
        for (int o = 32; o > 0; o >>= 1) zv += __shfl_xor(zv, o, 64);
        if (threadIdx.x == 0) zsh = zv;
    }
    __syncthreads();

    const float z  = zsh * ((float)NDATA / (64.0f * (float)KP1));
    const float rz = 1.0f / z;
    const float* ex = ex_in + (size_t)sb * KP1;

    float part = 0.f;
    for (int k = chunk * 256 + threadIdx.x; k < KP1; k += 512) {
        const float x = ex[k] * rz;
        if (k == 0) part += __logf(x / (x + M_CONST + EPS_C));
        else        part += __logf(M_CONST / (x + M_CONST + EPS_C));
    }
#pragma unroll
    for (int o = 32; o > 0; o >>= 1) part += __shfl_xor(part, o, 64);
    __shared__ float pw[4];
    if ((threadIdx.x & 63) == 0) pw[threadIdx.x >> 6] = part;
    __syncthreads();
    if (threadIdx.x == 0)
        atomicAdd(out, -(pw[0] + pw[1] + pw[2] + pw[3]) * (1.0f / 64.0f));
}

// ---------------------------------------------------------------------------
extern "C" void kernel_launch(void* const* d_in, const int* in_sizes, int n_in,
                              void* d_out, int out_size, void* d_ws, size_t ws_size,
                              hipStream_t stream)
{
    const float* feat_s     = (const float*)d_in[0];
    const float* feat_t     = (const float*)d_in[1];
    /* d_in[2] = idx, unused: sample_idx[:,0] already holds it */
    const int*   sample_idx = (const int*)  d_in[3];
    const float* w_s        = (const float*)d_in[4];
    const float* b_s        = (const float*)d_in[5];
    const float* w_t        = (const float*)d_in[6];
    const float* b_t        = (const float*)d_in[7];
    const float* mem_v1     = (const float*)d_in[8];
    const float* mem_v2     = (const float*)d_in[9];
    float* out = (float*)d_out;

    // Workspace layout:
    //   [z: 128 f32 = 512 B]
    //   [ex: 2*64*16385 f32 = 8.39 MB]   (gather-write -> loss-read)
    //   [vplanes: 69632 B, ALIASES ex]   (embed-write -> gemm-read; lifetimes
    //                                     disjoint: gemm ends before gather)
    //   [E: 128*100000 f32 = 51.2 MB]    (transposed: E[sb][n])
    char*  ws     = (char*)d_ws;
    float* ws_z   = (float*)ws;
    float* ws_ex  = (float*)(ws + 512);
    char*  ws_vp  = (char*)(ws + 512);   // alias of ex region
    float* ws_E   = (float*)(ws + 512 + (size_t)2 * BATCH * KP1 * sizeof(float));

    // z/out zeroing folded into embed_kernel block 0
    embed_kernel<<<2 * BATCH, 1024, 0, stream>>>(feat_s, feat_t, w_s, b_s, w_t, b_t,
                                                 ws_vp, ws_z, out);
    gemm_exp_kernel<<<2 * NBLK, 512, 0, stream>>>(mem_v1, mem_v2, ws_vp, ws_E);
    gather_z_kernel<<<2 * BATCH * GCH, 256, 0, stream>>>(sample_idx, ws_E, ws_ex, ws_z);
    loss_kernel<<<2 * BATCH * 2, 256, 0, stream>>>(ws_ex, ws_z, out);
}

// Round 7
// 204.239 us; speedup vs baseline: 1.2967x; 1.0022x over previous
//
#include <hip/hip_runtime.h>

// Problem constants (from reference)
#define DIM_IN   2048
#define FEAT     128
#define KP1      16385      // NCE_N + 1
#define NDATA    100000
#define BATCH    64
#define NB       128        // bank rows per gemm block
#define NBLK     ((NDATA + NB - 1) / NB)   // 782
#define GCH      16         // k-chunks per (side,b) in gather kernel

constexpr float NCE_T_INV = 1.0f / 0.07f;
constexpr float M_CONST   = 16384.0f / 100000.0f;   // NCE_N / N_DATA
constexpr float EPS_C     = 1e-7f;

typedef short bf16x8 __attribute__((ext_vector_type(8)));   // 8 bf16 = 4 VGPR
typedef float f32x4  __attribute__((ext_vector_type(4)));   // MFMA acc

// vplanes global layout (bytes), written by embed, DMA'd linearly by gemm:
//   plane(hi=0,lo=1)*34816 + side*17408 + anchor*272 + k*2
#define VP_PLANE 34816
#define VP_SIDE  17408
#define VP_ROW   272

// ---------------------------------------------------------------------------
// Kernel 1: h = l2norm(feat @ w.T + b), emitted as SPLIT-bf16 planes.
// 1024 threads (16 waves): verified round 5 (dropped 50 -> <42 us).
// Block 0 additionally zeroes z[128] and out.
// ---------------------------------------------------------------------------
__global__ void __launch_bounds__(1024) embed_kernel(
    const float* __restrict__ feat_s, const float* __restrict__ feat_t,
    const float* __restrict__ w_s, const float* __restrict__ b_s,
    const float* __restrict__ w_t, const float* __restrict__ b_t,
    char* __restrict__ vplanes, float* __restrict__ z_zero,
    float* __restrict__ out_zero)
{
    const int blk  = blockIdx.x;      // side*64 + b
    const int side = blk >> 6;
    const int b    = blk & 63;
    const float* feat = (side == 0 ? feat_s : feat_t) + (size_t)b * DIM_IN;
    const float* w    = (side == 0 ? w_s : w_t);
    const float* bias = (side == 0 ? b_s : b_t);

    __shared__ float sfeat[DIM_IN];
    __shared__ float pre[FEAT];
    __shared__ float wsum[2];

    const int t = threadIdx.x;
    if (blk == 0) {                   // fold the memsets into this launch
        if (t < 128) z_zero[t] = 0.f;
        else if (t == 128) out_zero[0] = 0.f;
    }
    {   // coalesced float4 stage of the feat row (8 KB, 512 float4)
        const float4* f4 = (const float4*)feat;
        float4* s4 = (float4*)sfeat;
        if (t < 512) s4[t] = f4[t];
    }
    __syncthreads();

    const int wv = t >> 6, ln = t & 63;   // 16 waves
    const float4* w4  = (const float4*)w;
    const float4* sf4 = (const float4*)sfeat;
#pragma unroll 2
    for (int i = 0; i < 8; ++i) {         // d = wv + 16*i: 8 iters/wave
        const int d = wv + i * 16;
        float s = 0.f;
#pragma unroll
        for (int seg = 0; seg < 8; ++seg) {  // 512 float4 per row / 64 lanes
            float4 a = w4[d * (DIM_IN / 4) + seg * 64 + ln];
            float4 f = sf4[seg * 64 + ln];
            s += a.x * f.x + a.y * f.y + a.z * f.z + a.w * f.w;
        }
#pragma unroll
        for (int o = 32; o > 0; o >>= 1) s += __shfl_xor(s, o, 64);
        if (ln == 0) pre[d] = s;
    }
    __syncthreads();

    if (t < 128) {
        float p = pre[t] + bias[t];
        pre[t] = p;
        float sq = p * p;
#pragma unroll
        for (int o = 32; o > 0; o >>= 1) sq += __shfl_xor(sq, o, 64);
        if ((t & 63) == 0) wsum[t >> 6] = sq;
    }
    __syncthreads();
    if (t < 128) {
        float inv_norm = 1.0f / sqrtf(wsum[0] + wsum[1]);
        float x = pre[t] * inv_norm;
        unsigned int u = __float_as_uint(x);
        unsigned short h = (unsigned short)(u >> 16);
        float hf = __uint_as_float(u & 0xffff0000u);
        float lr = x - hf;                         // exact in fp32
        unsigned short l = (unsigned short)(__float_as_uint(lr) >> 16);
        const size_t off = (size_t)side * VP_SIDE + (size_t)b * VP_ROW + t * 2;
        *(unsigned short*)(vplanes + off)            = h;
        *(unsigned short*)(vplanes + VP_PLANE + off) = l;
    }
}

// ---------------------------------------------------------------------------
// Kernel 2 (B-PATH REWRITE): E[sb][n] = exp(dot(bank[n], v[sb])/T).
// Round-5 post-mortem: 46 us at HBM 2.2 TB/s (floor 16.3 us for the exact
// 50+50 MB traffic), MfmaUtil 7.5%, 2.8M LDS bank-conflict cycles -- the
// B global->reg->LDS->reg round-trip dribbled bank fetches in 4 barrier-
// gated bites; queue depth too shallow for BW x latency.
// KEY FACT: the MFMA B-fragment for lane (nloc,kb) is exactly
// bank[n0+nloc][c*32+kb*8..+8] -- per-lane addressable. So B skips LDS
// entirely: each lane prefetches its WHOLE 128 B row slice (8 float4, all
// 4 chunks) before the single barrier, converts to split-bf16 hi/lo in
// registers per chunk, and feeds MFMA directly.
//   - removes all B ds_writes/ds_reads, the 20 KB x2 double-buffer, and 4
//     of 5 barriers; LDS = A planes only (34816 B).
//   - per-CU bytes in flight: ~64 KB burst vs ~16 KB -> latency covered.
//   - A: vplanes padded-272B rows DMA'd linearly (global_load_lds);
//     fragment read quads (lm+kb) mod 8 uniform -> conflict-free.
//   - split-precision bf16x3: C = Ah*Bh + Al*Bh + Ah*Bl (verified r4/r5,
//     absmax 0.0).
//   - C/D: col=lane&15 -> bank row n, row=(lane>>4)*4+reg -> anchor (m89).
// ---------------------------------------------------------------------------
__global__ void __launch_bounds__(512) gemm_exp_kernel(
    const float* __restrict__ mem_v1, const float* __restrict__ mem_v2,
    const char* __restrict__ vplanes, float* __restrict__ E)
{
    // LDS map (bytes): [0,17408) A hi : anchor*272 + k*2 ; [17408,34816) A lo
    __shared__ __align__(16) char lds[34816];

    const int bx   = blockIdx.x;
    const int side = bx & 1;
    const int tile = bx >> 1;
    const int n0   = tile * NB;
    const float* bank = (side == 0 ? mem_v2 : mem_v1);
    const int t  = threadIdx.x;
    const int wv = t >> 6, ln = t & 63;
    const int lm = ln & 15;           // MFMA lane index: n within 16-group
    const int kb = ln >> 4;           // MFMA k-block (0..3)
    const int nloc = wv * 16 + lm;    // tile-local bank row this lane owns

    // ---- B: per-lane prefetch of the full row slice (8 float4) ---------
    int rowg = n0 + nloc; if (rowg > NDATA - 1) rowg = NDATA - 1;
    const float* bsrc = bank + (size_t)rowg * FEAT;
    float4 bq[8];
#pragma unroll
    for (int c = 0; c < 4; ++c) {
        const float4* p = (const float4*)(bsrc + c * 32 + kb * 8);
        bq[c * 2 + 0] = p[0];
        bq[c * 2 + 1] = p[1];
    }

    // ---- A planes: linear DMA, 34 segments x 1024 B --------------------
    {
        const char* hbase = vplanes + (size_t)side * VP_SIDE;
        const char* lbase = vplanes + VP_PLANE + (size_t)side * VP_SIDE;
        for (int seg = wv; seg < 34; seg += 8) {
            const char* src = (seg < 17 ? hbase + seg * 1024
                                        : lbase + (seg - 17) * 1024) + ln * 16;
            __builtin_amdgcn_global_load_lds(
                (const __attribute__((address_space(1))) void*)src,
                (__attribute__((address_space(3))) void*)(lds + seg * 1024),
                16, 0, 0);
        }
    }

    f32x4 acc[4];
#pragma unroll
    for (int mi = 0; mi < 4; ++mi) acc[mi] = (f32x4){0.f, 0.f, 0.f, 0.f};

    __syncthreads();    // drains A DMA (vmcnt) -- B loads drain too (needed now)

#pragma unroll
    for (int c = 0; c < 4; ++c) {
        // convert this chunk's 8 floats -> split hi/lo bf16x8 (static idx)
        const float xs[8] = {bq[c*2].x,   bq[c*2].y,   bq[c*2].z,   bq[c*2].w,
                             bq[c*2+1].x, bq[c*2+1].y, bq[c*2+1].z, bq[c*2+1].w};
        bf16x8 bh, bl;
#pragma unroll
        for (int j = 0; j < 8; ++j) {
            unsigned int u = __float_as_uint(xs[j]);
            bh[j] = (short)(u >> 16);
            float hf = __uint_as_float(u & 0xffff0000u);
            bl[j] = (short)(__float_as_uint(xs[j] - hf) >> 16);
        }
        // A fragments
        bf16x8 ah[4], al[4];
#pragma unroll
        for (int mi = 0; mi < 4; ++mi) {
            ah[mi] = *(const bf16x8*)(lds + (mi * 16 + lm) * VP_ROW + c * 64 + kb * 16);
            al[mi] = *(const bf16x8*)(lds + 17408 + (mi * 16 + lm) * VP_ROW + c * 64 + kb * 16);
        }
        // 3-term split-precision MFMA
#pragma unroll
        for (int mi = 0; mi < 4; ++mi) {
            acc[mi] = __builtin_amdgcn_mfma_f32_16x16x32_bf16(ah[mi], bh, acc[mi], 0, 0, 0);
            acc[mi] = __builtin_amdgcn_mfma_f32_16x16x32_bf16(al[mi], bh, acc[mi], 0, 0, 0);
            acc[mi] = __builtin_amdgcn_mfma_f32_16x16x32_bf16(ah[mi], bl, acc[mi], 0, 0, 0);
        }
    }

    // epilogue: exp + store. col=lane&15 -> n, row=(lane>>4)*4+reg -> anchor.
    const int nn = n0 + nloc;
    if (nn < NDATA) {
#pragma unroll
        for (int mi = 0; mi < 4; ++mi)
#pragma unroll
            for (int j = 0; j < 4; ++j) {
                const int anchor = mi * 16 + kb * 4 + j;
                E[(size_t)(side * 64 + anchor) * NDATA + nn] =
                    __expf(acc[mi][j] * NCE_T_INV);
            }
    }
}

// ---------------------------------------------------------------------------
// Kernel 3: gather ex = E[sb][idx[b,k]], store compact, accumulate Z[sb].
// GCH=16: latency-bound random 4B reads; 32 waves in flight per CU.
// blk&127 = sb keeps a given sb's chunks on one XCD.
// ---------------------------------------------------------------------------
__global__ void __launch_bounds__(256) gather_z_kernel(
    const int* __restrict__ sample_idx, const float* __restrict__ E,
    float* __restrict__ ex_out, float* __restrict__ z_out)
{
    const int blk   = blockIdx.x;
    const int chunk = blk >> 7;          // 0..GCH-1
    const int sb    = blk & 127;         // side*64 + b
    const int b     = sb & 63;
    const float* Eb = E + (size_t)sb * NDATA;

    float zp = 0.f;
    for (int k = chunk * 256 + threadIdx.x; k < KP1; k += GCH * 256) {
        const int idx = sample_idx[(size_t)b * KP1 + k];
        const float e = Eb[idx];
        ex_out[(size_t)sb * KP1 + k] = e;
        zp += e;
    }
#pragma unroll
    for (int o = 32; o > 0; o >>= 1) zp += __shfl_xor(zp, o, 64);
    __shared__ float zw[4];
    if ((threadIdx.x & 63) == 0) zw[threadIdx.x >> 6] = zp;
    __syncthreads();
    if (threadIdx.x == 0) atomicAdd(&z_out[sb], zw[0] + zw[1] + zw[2] + zw[3]);
}

// ---------------------------------------------------------------------------
// Kernel 4: loss. 256 blocks (2 chunks x 128 sb). Z summed in-kernel from
// the 64 per-sb partials of this side; 256 output atomics total.
// ---------------------------------------------------------------------------
__global__ void __launch_bounds__(256) loss_kernel(
    const float* __restrict__ ex_in, const float* __restrict__ z_in,
    float* __restrict__ out)
{
    const int blk   = blockIdx.x;
    const int chunk = blk >> 7;          // 0..1
    const int sb    = blk & 127;
    const int side  = sb >> 6;

    __shared__ float zsh;
    if (threadIdx.x < 64) {
        float zv = z_in[side * 64 + threadIdx.x];
#pragma unroll
        for (int o = 32; o > 0; o >>= 1) zv += __shfl_xor(zv, o, 64);
        if (threadIdx.x == 0) zsh = zv;
    }
    __syncthreads();

    const float z  = zsh * ((float)NDATA / (64.0f * (float)KP1));
    const float rz = 1.0f / z;
    const float* ex = ex_in + (size_t)sb * KP1;

    float part = 0.f;
    for (int k = chunk * 256 + threadIdx.x; k < KP1; k += 512) {
        const float x = ex[k] * rz;
        if (k == 0) part += __logf(x / (x + M_CONST + EPS_C));
        else        part += __logf(M_CONST / (x + M_CONST + EPS_C));
    }
#pragma unroll
    for (int o = 32; o > 0; o >>= 1) part += __shfl_xor(part, o, 64);
    __shared__ float pw[4];
    if ((threadIdx.x & 63) == 0) pw[threadIdx.x >> 6] = part;
    __syncthreads();
    if (threadIdx.x == 0)
        atomicAdd(out, -(pw[0] + pw[1] + pw[2] + pw[3]) * (1.0f / 64.0f));
}

// ---------------------------------------------------------------------------
extern "C" void kernel_launch(void* const* d_in, const int* in_sizes, int n_in,
                              void* d_out, int out_size, void* d_ws, size_t ws_size,
                              hipStream_t stream)
{
    const float* feat_s     = (const float*)d_in[0];
    const float* feat_t     = (const float*)d_in[1];
    /* d_in[2] = idx, unused: sample_idx[:,0] already holds it */
    const int*   sample_idx = (const int*)  d_in[3];
    const float* w_s        = (const float*)d_in[4];
    const float* b_s        = (const float*)d_in[5];
    const float* w_t        = (const float*)d_in[6];
    const float* b_t        = (const float*)d_in[7];
    const float* mem_v1     = (const float*)d_in[8];
    const float* mem_v2     = (const float*)d_in[9];
    float* out = (float*)d_out;

    // Workspace layout:
    //   [z: 128 f32 = 512 B]
    //   [ex: 2*64*16385 f32 = 8.39 MB]   (gather-write -> loss-read)
    //   [vplanes: 69632 B, ALIASES ex]   (embed-write -> gemm-read; lifetimes
    //                                     disjoint: gemm ends before gather)
    //   [E: 128*100000 f32 = 51.2 MB]    (transposed: E[sb][n])
    char*  ws     = (char*)d_ws;
    float* ws_z   = (float*)ws;
    float* ws_ex  = (float*)(ws + 512);
    char*  ws_vp  = (char*)(ws + 512);   // alias of ex region
    float* ws_E   = (float*)(ws + 512 + (size_t)2 * BATCH * KP1 * sizeof(float));

    // z/out zeroing folded into embed_kernel block 0
    embed_kernel<<<2 * BATCH, 1024, 0, stream>>>(feat_s, feat_t, w_s, b_s, w_t, b_t,
                                                 ws_vp, ws_z, out);
    gemm_exp_kernel<<<2 * NBLK, 512, 0, stream>>>(mem_v1, mem_v2, ws_vp, ws_E);
    gather_z_kernel<<<2 * BATCH * GCH, 256, 0, stream>>>(sample_idx, ws_E, ws_ex, ws_z);
    loss_kernel<<<2 * BATCH * 2, 256, 0, stream>>>(ws_ex, ws_z, out);
}